// Round 3
// baseline (259.706 us; speedup 1.0000x reference)
//
#include <hip/hip_runtime.h>
#include <math.h>

#define SCALING 0.125f

typedef __attribute__((ext_vector_type(8))) short short8;
typedef __attribute__((ext_vector_type(4))) float f32x4;

// round-to-nearest-even fp32 -> bf16 (single value)
static __device__ __forceinline__ unsigned short bf16r(float x) {
  unsigned int u = __float_as_uint(x);
  u += 0x7fffu + ((u >> 16) & 1u);
  return (unsigned short)(u >> 16);
}
// pack two fp32 -> bf16x2 (lo in low 16 bits) via v_perm_b32 merge
static __device__ __forceinline__ unsigned int pk_bf16(float lo, float hi) {
  unsigned int ua = __float_as_uint(lo);
  unsigned int ub = __float_as_uint(hi);
  ua += 0x7fffu + ((ua >> 16) & 1u);
  ub += 0x7fffu + ((ub >> 16) & 1u);
  return __builtin_amdgcn_perm(ub, ua, 0x07060302u);
}

// ---------------------------------------------------------------------------
// Kernel A: packed in-projection GEMM -> per-head layouts.
//   j <  512 : q -> qh[i][t][hd] fp32  (scaled by 0.125)
//   j < 1024 : k -> kh[i][t][hd] fp32
//   j < 1536 : v -> vh[i][t][hd] bf16  (rounded once here)
// ---------------------------------------------------------------------------
__global__ __launch_bounds__(256)
void proj_kernel(const float* __restrict__ query,
                 const float* __restrict__ key,
                 const float* __restrict__ value,
                 const float* __restrict__ W,
                 const float* __restrict__ bias,
                 float* __restrict__ qh,
                 float* __restrict__ kh,
                 unsigned short* __restrict__ vh) {
  __shared__ float Xs[16][68];
  __shared__ float Ws[16][68];
  const int r0 = blockIdx.y * 64;
  const int c0 = blockIdx.x * 64;
  const int g = c0 >> 9;  // 0=q,1=k,2=v (uniform per block)
  const float* __restrict__ X = (g == 0) ? query : (g == 1) ? key : value;
  const int tid = threadIdx.x;
  const int lrow = tid >> 2;
  const int lk4 = (tid & 3) * 4;
  const int tr = tid >> 4;
  const int tc = tid & 15;

  float acc[4][4] = {};
  for (int kt = 0; kt < 512; kt += 16) {
    float4 xv = *(const float4*)&X[(r0 + lrow) * 512 + kt + lk4];
    float4 wv = *(const float4*)&W[(c0 + lrow) * 512 + kt + lk4];
    __syncthreads();
    Xs[lk4 + 0][lrow] = xv.x; Xs[lk4 + 1][lrow] = xv.y;
    Xs[lk4 + 2][lrow] = xv.z; Xs[lk4 + 3][lrow] = xv.w;
    Ws[lk4 + 0][lrow] = wv.x; Ws[lk4 + 1][lrow] = wv.y;
    Ws[lk4 + 2][lrow] = wv.z; Ws[lk4 + 3][lrow] = wv.w;
    __syncthreads();
#pragma unroll
    for (int kk = 0; kk < 16; kk++) {
      float a[4], b[4];
      *(float4*)a = *(const float4*)&Xs[kk][tr * 4];
      *(float4*)b = *(const float4*)&Ws[kk][tc * 4];
#pragma unroll
      for (int ri = 0; ri < 4; ri++)
#pragma unroll
        for (int cj = 0; cj < 4; cj++)
          acc[ri][cj] = fmaf(a[ri], b[cj], acc[ri][cj]);
    }
  }

#pragma unroll
  for (int ri = 0; ri < 4; ri++) {
    const int r = r0 + tr * 4 + ri;
    const int t = r >> 3;
    const int batch = r & 7;
#pragma unroll
    for (int cj = 0; cj < 4; cj++) {
      const int j = c0 + tc * 4 + cj;
      float val = acc[ri][cj] + bias[j];
      const int jj = j & 511;
      const int head = jj >> 6;
      const int hd = jj & 63;
      const int i = batch * 8 + head;
      const int idx = ((i << 7) + t) * 64 + hd;
      if (g == 0)      qh[idx] = val * SCALING;
      else if (g == 1) kh[idx] = val;
      else             vh[idx] = bf16r(val);
    }
  }
}

// ---------------------------------------------------------------------------
// Kernel B: one block per (batch, a, head). Trilinear cube via bf16 MFMA,
// fused bias add + mean/max over c, then block-level softmax over b and
// attn[i,a,:] = sum_b w[b]*q[i,b,:]. No fused/softmax round-trip to HBM.
// MFMA inner loop + bias epilogue identical to the verified round-2 kernel.
// ---------------------------------------------------------------------------
__global__ __launch_bounds__(256, 4)
void score_kernel(const float* __restrict__ qh,
                  const float* __restrict__ kh,
                  const unsigned short* __restrict__ vh,
                  const float* __restrict__ cbias,
                  float* __restrict__ attn) {
  __shared__ __align__(16) unsigned short Ks[128 * 72];
  __shared__ __align__(16) unsigned short Vs[128 * 72];
  __shared__ float rowLds[128];
  __shared__ float wLds[128];
  __shared__ float partial[4][64];

  const int bid = blockIdx.x;          // ((batch*128 + a)*8) + h
  const int h = bid & 7;
  const int ab = bid >> 3;
  const int batch = ab >> 7;
  const int a = ab & 127;
  const int i = batch * 8 + h;
  const int tid = threadIdx.x;
  const int w = tid >> 6;
  const int lane = tid & 63;
  const int quad = lane >> 4;
  const int n15 = lane & 15;

  const float* __restrict__ bp = cbias + (size_t)ab * 16384;
  const float* __restrict__ kb = kh + (size_t)i * 8192;
  const uint4* __restrict__ vb4 = (const uint4*)(vh + (size_t)i * 8192);
  const float* __restrict__ qa = qh + ((size_t)i * 128 + a) * 64;

  // ---- stage: Vs (copy) + Ks (k * q_a, packed bf16) ----
  const int col8 = (tid & 7) * 8;  // j-invariant
  f32x4 q0 = *(const f32x4*)&qa[col8];
  f32x4 q1 = *(const f32x4*)&qa[col8 + 4];
#pragma unroll
  for (int j = 0; j < 4; ++j) {
    const int gg = j * 256 + tid;  // 0..1023 groups of 8 elements
    const int row = gg >> 3;
    *(uint4*)&Vs[row * 72 + col8] = vb4[gg];
    f32x4 k0 = *(const f32x4*)&kb[8 * gg];
    f32x4 k1 = *(const f32x4*)&kb[8 * gg + 4];
    k0 *= q0;
    k1 *= q1;
    uint4 pk;
    pk.x = pk_bf16(k0[0], k0[1]);
    pk.y = pk_bf16(k0[2], k0[3]);
    pk.z = pk_bf16(k1[0], k1[1]);
    pk.w = pk_bf16(k1[2], k1[3]);
    *(uint4*)&Ks[row * 72 + col8] = pk;
  }
  __syncthreads();

  // ---- MFMA: S^T[c,b] = sum_hd v[c,hd] * (k[b,hd]*qa[hd]) ----
  short8 bf[2][2];
#pragma unroll
  for (int jb = 0; jb < 2; ++jb)
#pragma unroll
    for (int kk = 0; kk < 2; ++kk)
      bf[jb][kk] =
          *(const short8*)&Ks[(w * 32 + jb * 16 + n15) * 72 + kk * 32 + quad * 8];

  f32x4 acc[8][2];
#pragma unroll
  for (int ic = 0; ic < 8; ++ic)
#pragma unroll
    for (int jb = 0; jb < 2; ++jb) acc[ic][jb] = (f32x4){0.f, 0.f, 0.f, 0.f};

#pragma unroll
  for (int ic = 0; ic < 8; ++ic) {
    short8 a0 = *(const short8*)&Vs[(ic * 16 + n15) * 72 + quad * 8];
    short8 a1 = *(const short8*)&Vs[(ic * 16 + n15) * 72 + 32 + quad * 8];
    acc[ic][0] = __builtin_amdgcn_mfma_f32_16x16x32_bf16(a0, bf[0][0], acc[ic][0], 0, 0, 0);
    acc[ic][0] = __builtin_amdgcn_mfma_f32_16x16x32_bf16(a1, bf[0][1], acc[ic][0], 0, 0, 0);
    acc[ic][1] = __builtin_amdgcn_mfma_f32_16x16x32_bf16(a0, bf[1][0], acc[ic][1], 0, 0, 0);
    acc[ic][1] = __builtin_amdgcn_mfma_f32_16x16x32_bf16(a1, bf[1][1], acc[ic][1], 0, 0, 0);
  }

  // ---- bias add + mean/max over c, cross-quad reduce ----
  float fsum[2] = {0.f, 0.f};
  float fmx[2] = {-INFINITY, -INFINITY};
#pragma unroll
  for (int ic = 0; ic < 8; ++ic)
#pragma unroll
    for (int jb = 0; jb < 2; ++jb) {
      const int b = w * 32 + jb * 16 + n15;
      f32x4 bb = *(const f32x4*)&bp[b * 128 + ic * 16 + quad * 4];
#pragma unroll
      for (int r = 0; r < 4; ++r) {
        const float v = acc[ic][jb][r] + bb[r];
        fsum[jb] += v;
        fmx[jb] = fmaxf(fmx[jb], v);
      }
    }
#pragma unroll
  for (int off = 16; off <= 32; off <<= 1) {
#pragma unroll
    for (int jb = 0; jb < 2; ++jb) {
      fsum[jb] += __shfl_xor(fsum[jb], off, 64);
      fmx[jb] = fmaxf(fmx[jb], __shfl_xor(fmx[jb], off, 64));
    }
  }
  if (quad == 0) {
    rowLds[w * 32 + n15] = fsum[0] * (1.0f / 128.0f) + fmx[0];
    rowLds[w * 32 + 16 + n15] = fsum[1] * (1.0f / 128.0f) + fmx[1];
  }
  __syncthreads();

  // ---- softmax over b (wave 0) ----
  if (w == 0) {
    float f0 = rowLds[lane], f1 = rowLds[lane + 64];
    float m = fmaxf(f0, f1);
#pragma unroll
    for (int off = 32; off >= 1; off >>= 1) m = fmaxf(m, __shfl_xor(m, off, 64));
    const float e0 = expf(f0 - m), e1 = expf(f1 - m);
    float s = e0 + e1;
#pragma unroll
    for (int off = 32; off >= 1; off >>= 1) s += __shfl_xor(s, off, 64);
    const float inv = 1.0f / s;
    wLds[lane] = e0 * inv;
    wLds[lane + 64] = e1 * inv;
  }
  __syncthreads();

  // ---- attn[i,a,hd] = sum_b w[b] * qh[i][b][hd] ----
  {
    const float* __restrict__ qp = qh + (size_t)i * 8192 + lane;
    float acc2 = 0.f;
#pragma unroll 4
    for (int b = 0; b < 32; ++b)
      acc2 = fmaf(wLds[w * 32 + b], qp[(w * 32 + b) * 64], acc2);
    partial[w][lane] = acc2;
  }
  __syncthreads();
  if (w == 0) {
    const float o =
        partial[0][lane] + partial[1][lane] + partial[2][lane] + partial[3][lane];
    attn[((size_t)a * 8 + batch) * 512 + h * 64 + lane] = o;
  }
}

// ---------------------------------------------------------------------------
// Kernel D: output projection. out[r,j] = sum_m attn[r,m]*out_w[j,m] + out_b[j]
// ---------------------------------------------------------------------------
__global__ __launch_bounds__(256)
void outproj_kernel(const float* __restrict__ Xa,
                    const float* __restrict__ W,
                    const float* __restrict__ bias,
                    float* __restrict__ out) {
  __shared__ float Xs[16][68];
  __shared__ float Ws[16][68];
  const int r0 = blockIdx.y * 64;
  const int c0 = blockIdx.x * 64;
  const int tid = threadIdx.x;
  const int lrow = tid >> 2;
  const int lk4 = (tid & 3) * 4;
  const int tr = tid >> 4;
  const int tc = tid & 15;

  float acc[4][4] = {};
  for (int kt = 0; kt < 512; kt += 16) {
    float4 xv = *(const float4*)&Xa[(r0 + lrow) * 512 + kt + lk4];
    float4 wv = *(const float4*)&W[(c0 + lrow) * 512 + kt + lk4];
    __syncthreads();
    Xs[lk4 + 0][lrow] = xv.x; Xs[lk4 + 1][lrow] = xv.y;
    Xs[lk4 + 2][lrow] = xv.z; Xs[lk4 + 3][lrow] = xv.w;
    Ws[lk4 + 0][lrow] = wv.x; Ws[lk4 + 1][lrow] = wv.y;
    Ws[lk4 + 2][lrow] = wv.z; Ws[lk4 + 3][lrow] = wv.w;
    __syncthreads();
#pragma unroll
    for (int kk = 0; kk < 16; kk++) {
      float a[4], b[4];
      *(float4*)a = *(const float4*)&Xs[kk][tr * 4];
      *(float4*)b = *(const float4*)&Ws[kk][tc * 4];
#pragma unroll
      for (int ri = 0; ri < 4; ri++)
#pragma unroll
        for (int cj = 0; cj < 4; cj++)
          acc[ri][cj] = fmaf(a[ri], b[cj], acc[ri][cj]);
    }
  }
#pragma unroll
  for (int ri = 0; ri < 4; ri++) {
    const int r = r0 + tr * 4 + ri;
#pragma unroll
    for (int cj = 0; cj < 4; cj++) {
      const int j = c0 + tc * 4 + cj;
      out[(size_t)r * 512 + j] = acc[ri][cj] + bias[j];
    }
  }
}

extern "C" void kernel_launch(void* const* d_in, const int* in_sizes, int n_in,
                              void* d_out, int out_size, void* d_ws,
                              size_t ws_size, hipStream_t stream) {
  const float* query = (const float*)d_in[0];
  const float* key   = (const float*)d_in[1];
  const float* value = (const float*)d_in[2];
  const float* cbias = (const float*)d_in[3];
  const float* W     = (const float*)d_in[4];
  const float* pb    = (const float*)d_in[5];
  const float* out_w = (const float*)d_in[6];
  const float* out_b = (const float*)d_in[7];
  float* out = (float*)d_out;

  float* ws = (float*)d_ws;
  float* qh = ws;                                        // 524288 f
  float* kh = ws + 524288;                               // 524288 f
  unsigned short* vh = (unsigned short*)(ws + 1048576);  // 524288 bf16
  float* attn = ws + 1048576 + 262144;                   // 524288 f

  proj_kernel<<<dim3(24, 16), 256, 0, stream>>>(query, key, value, W, pb, qh,
                                                kh, vh);
  score_kernel<<<8192, 256, 0, stream>>>(qh, kh, vh, cbias, attn);
  outproj_kernel<<<dim3(8, 16), 256, 0, stream>>>(attn, out_w, out_b, out);
}

// Round 4
// 237.075 us; speedup vs baseline: 1.0955x; 1.0955x over previous
//
#include <hip/hip_runtime.h>
#include <math.h>

#define SCALING 0.125f

typedef __attribute__((ext_vector_type(8))) short short8;
typedef __attribute__((ext_vector_type(4))) float f32x4;

// round-to-nearest-even fp32 -> bf16 (single value)
static __device__ __forceinline__ unsigned short bf16r(float x) {
  unsigned int u = __float_as_uint(x);
  u += 0x7fffu + ((u >> 16) & 1u);
  return (unsigned short)(u >> 16);
}
// pack two fp32 -> bf16x2 (lo in low 16 bits) via v_perm_b32 merge
static __device__ __forceinline__ unsigned int pk_bf16(float lo, float hi) {
  unsigned int ua = __float_as_uint(lo);
  unsigned int ub = __float_as_uint(hi);
  ua += 0x7fffu + ((ua >> 16) & 1u);
  ub += 0x7fffu + ((ub >> 16) & 1u);
  return __builtin_amdgcn_perm(ub, ua, 0x07060302u);
}

// ---------------------------------------------------------------------------
// Kernel A: packed in-projection GEMM -> per-head layouts.
//   j <  512 : q -> qh[i][t][hd] fp32  (scaled by 0.125)
//   j < 1024 : k -> kh[i][t][hd] fp32
//   j < 1536 : v -> vh[i][t][hd] bf16  (rounded once here)
// ---------------------------------------------------------------------------
__global__ __launch_bounds__(256)
void proj_kernel(const float* __restrict__ query,
                 const float* __restrict__ key,
                 const float* __restrict__ value,
                 const float* __restrict__ W,
                 const float* __restrict__ bias,
                 float* __restrict__ qh,
                 float* __restrict__ kh,
                 unsigned short* __restrict__ vh) {
  __shared__ float Xs[16][68];
  __shared__ float Ws[16][68];
  const int r0 = blockIdx.y * 64;
  const int c0 = blockIdx.x * 64;
  const int g = c0 >> 9;  // 0=q,1=k,2=v (uniform per block)
  const float* __restrict__ X = (g == 0) ? query : (g == 1) ? key : value;
  const int tid = threadIdx.x;
  const int lrow = tid >> 2;
  const int lk4 = (tid & 3) * 4;
  const int tr = tid >> 4;
  const int tc = tid & 15;

  float acc[4][4] = {};
  for (int kt = 0; kt < 512; kt += 16) {
    float4 xv = *(const float4*)&X[(r0 + lrow) * 512 + kt + lk4];
    float4 wv = *(const float4*)&W[(c0 + lrow) * 512 + kt + lk4];
    __syncthreads();
    Xs[lk4 + 0][lrow] = xv.x; Xs[lk4 + 1][lrow] = xv.y;
    Xs[lk4 + 2][lrow] = xv.z; Xs[lk4 + 3][lrow] = xv.w;
    Ws[lk4 + 0][lrow] = wv.x; Ws[lk4 + 1][lrow] = wv.y;
    Ws[lk4 + 2][lrow] = wv.z; Ws[lk4 + 3][lrow] = wv.w;
    __syncthreads();
#pragma unroll
    for (int kk = 0; kk < 16; kk++) {
      float a[4], b[4];
      *(float4*)a = *(const float4*)&Xs[kk][tr * 4];
      *(float4*)b = *(const float4*)&Ws[kk][tc * 4];
#pragma unroll
      for (int ri = 0; ri < 4; ri++)
#pragma unroll
        for (int cj = 0; cj < 4; cj++)
          acc[ri][cj] = fmaf(a[ri], b[cj], acc[ri][cj]);
    }
  }

#pragma unroll
  for (int ri = 0; ri < 4; ri++) {
    const int r = r0 + tr * 4 + ri;
    const int t = r >> 3;
    const int batch = r & 7;
#pragma unroll
    for (int cj = 0; cj < 4; cj++) {
      const int j = c0 + tc * 4 + cj;
      float val = acc[ri][cj] + bias[j];
      const int jj = j & 511;
      const int head = jj >> 6;
      const int hd = jj & 63;
      const int i = batch * 8 + head;
      const int idx = ((i << 7) + t) * 64 + hd;
      if (g == 0)      qh[idx] = val * SCALING;
      else if (g == 1) kh[idx] = val;
      else             vh[idx] = bf16r(val);
    }
  }
}

// ---------------------------------------------------------------------------
// Kernel B: one block per (batch, a); loops 8 heads (bias-slice reuse!).
// Bias fragment preloaded ONCE into 64 VGPRs (16 x float4 matching the
// accumulator fragment coords, which are head-invariant) -> epilogue is pure
// VALU, no per-head L2 bias traffic. Fused softmax over b + attn bmm.
// MFMA inner loop identical to the verified round-2/3 kernel.
// ---------------------------------------------------------------------------
__global__ __launch_bounds__(256)
void score_kernel(const float* __restrict__ qh,
                  const float* __restrict__ kh,
                  const unsigned short* __restrict__ vh,
                  const float* __restrict__ cbias,
                  float* __restrict__ attn) {
  __shared__ __align__(16) unsigned short Ks[128 * 72];
  __shared__ __align__(16) unsigned short Vs[128 * 72];
  __shared__ float rowLds[128];
  __shared__ float wLds[128];

  const int ab = blockIdx.x;  // batch*128 + a
  const int batch = ab >> 7;
  const int a = ab & 127;
  const int tid = threadIdx.x;
  const int w = tid >> 6;
  const int lane = tid & 63;
  const int quad = lane >> 4;
  const int n15 = lane & 15;
  const int col8 = (tid & 7) * 8;  // staging column (j-invariant)

  // ---- preload bias fragment into registers (head-invariant coords) ----
  const float* __restrict__ bp = cbias + (size_t)ab * 16384;
  f32x4 biasReg[8][2];
#pragma unroll
  for (int ic = 0; ic < 8; ++ic)
#pragma unroll
    for (int jb = 0; jb < 2; ++jb) {
      const int b = w * 32 + jb * 16 + n15;
      biasReg[ic][jb] = *(const f32x4*)&bp[b * 128 + ic * 16 + quad * 4];
    }

  for (int h = 0; h < 8; ++h) {
    const int i = batch * 8 + h;
    const float* __restrict__ kb = kh + (size_t)i * 8192;
    const uint4* __restrict__ vb4 = (const uint4*)(vh + (size_t)i * 8192);
    const float* __restrict__ qa = qh + ((size_t)i * 128 + a) * 64;

    // ---- stage: Vs (copy) + Ks (k * q_a, packed bf16) ----
    f32x4 q0 = *(const f32x4*)&qa[col8];
    f32x4 q1 = *(const f32x4*)&qa[col8 + 4];
#pragma unroll
    for (int j = 0; j < 4; ++j) {
      const int gg = j * 256 + tid;  // 0..1023 groups of 8 elements
      const int row = gg >> 3;
      *(uint4*)&Vs[row * 72 + col8] = vb4[gg];
      f32x4 k0 = *(const f32x4*)&kb[8 * gg];
      f32x4 k1 = *(const f32x4*)&kb[8 * gg + 4];
      k0 *= q0;
      k1 *= q1;
      uint4 pk;
      pk.x = pk_bf16(k0[0], k0[1]);
      pk.y = pk_bf16(k0[2], k0[3]);
      pk.z = pk_bf16(k1[0], k1[1]);
      pk.w = pk_bf16(k1[2], k1[3]);
      *(uint4*)&Ks[row * 72 + col8] = pk;
    }
    __syncthreads();

    // ---- MFMA: S^T[c,b] = sum_hd v[c,hd] * (k[b,hd]*qa[hd]) ----
    short8 bf[2][2];
#pragma unroll
    for (int jb = 0; jb < 2; ++jb)
#pragma unroll
      for (int kk = 0; kk < 2; ++kk)
        bf[jb][kk] = *(const short8*)&Ks[(w * 32 + jb * 16 + n15) * 72 +
                                         kk * 32 + quad * 8];

    f32x4 acc[8][2];
#pragma unroll
    for (int ic = 0; ic < 8; ++ic)
#pragma unroll
      for (int jb = 0; jb < 2; ++jb) acc[ic][jb] = (f32x4){0.f, 0.f, 0.f, 0.f};

#pragma unroll
    for (int ic = 0; ic < 8; ++ic) {
      short8 a0 = *(const short8*)&Vs[(ic * 16 + n15) * 72 + quad * 8];
      short8 a1 = *(const short8*)&Vs[(ic * 16 + n15) * 72 + 32 + quad * 8];
      acc[ic][0] = __builtin_amdgcn_mfma_f32_16x16x32_bf16(a0, bf[0][0], acc[ic][0], 0, 0, 0);
      acc[ic][0] = __builtin_amdgcn_mfma_f32_16x16x32_bf16(a1, bf[0][1], acc[ic][0], 0, 0, 0);
      acc[ic][1] = __builtin_amdgcn_mfma_f32_16x16x32_bf16(a0, bf[1][0], acc[ic][1], 0, 0, 0);
      acc[ic][1] = __builtin_amdgcn_mfma_f32_16x16x32_bf16(a1, bf[1][1], acc[ic][1], 0, 0, 0);
    }

    // ---- bias add (registers) + mean/max over c, cross-quad reduce ----
    float fsum[2] = {0.f, 0.f};
    float fmx[2] = {-INFINITY, -INFINITY};
#pragma unroll
    for (int ic = 0; ic < 8; ++ic)
#pragma unroll
      for (int jb = 0; jb < 2; ++jb) {
#pragma unroll
        for (int r = 0; r < 4; ++r) {
          const float v = acc[ic][jb][r] + biasReg[ic][jb][r];
          fsum[jb] += v;
          fmx[jb] = fmaxf(fmx[jb], v);
        }
      }
#pragma unroll
    for (int off = 16; off <= 32; off <<= 1) {
#pragma unroll
      for (int jb = 0; jb < 2; ++jb) {
        fsum[jb] += __shfl_xor(fsum[jb], off, 64);
        fmx[jb] = fmaxf(fmx[jb], __shfl_xor(fmx[jb], off, 64));
      }
    }
    if (quad == 0) {
      rowLds[w * 32 + n15] = fsum[0] * (1.0f / 128.0f) + fmx[0];
      rowLds[w * 32 + 16 + n15] = fsum[1] * (1.0f / 128.0f) + fmx[1];
    }
    __syncthreads();

    // ---- softmax over b (wave 0) ----
    if (w == 0) {
      float f0 = rowLds[lane], f1 = rowLds[lane + 64];
      float m = fmaxf(f0, f1);
#pragma unroll
      for (int off = 32; off >= 1; off >>= 1)
        m = fmaxf(m, __shfl_xor(m, off, 64));
      const float e0 = expf(f0 - m), e1 = expf(f1 - m);
      float s = e0 + e1;
#pragma unroll
      for (int off = 32; off >= 1; off >>= 1) s += __shfl_xor(s, off, 64);
      const float inv = 1.0f / s;
      wLds[lane] = e0 * inv;
      wLds[lane + 64] = e1 * inv;
    }
    __syncthreads();

    // ---- attn[i,a,hd] = sum_b w[b]*qh[i][b][hd]; wave w owns hd=w*16+n15,
    //      quad owns b-range [quad*32, quad*32+32); shfl-reduce across quads.
    {
      const int hd = w * 16 + n15;
      const float* __restrict__ qp = qh + (size_t)i * 8192 + hd;
      float acc2 = 0.f;
#pragma unroll 8
      for (int b = 0; b < 32; ++b) {
        const int bb = quad * 32 + b;
        acc2 = fmaf(wLds[bb], qp[bb * 64], acc2);
      }
      acc2 += __shfl_xor(acc2, 16, 64);
      acc2 += __shfl_xor(acc2, 32, 64);
      if (quad == 0)
        attn[((size_t)a * 8 + batch) * 512 + h * 64 + hd] = acc2;
    }
    __syncthreads();  // protect Ks/Vs/rowLds/wLds before next head's writes
  }
}

// ---------------------------------------------------------------------------
// Kernel D: output projection. out[r,j] = sum_m attn[r,m]*out_w[j,m] + out_b[j]
// ---------------------------------------------------------------------------
__global__ __launch_bounds__(256)
void outproj_kernel(const float* __restrict__ Xa,
                    const float* __restrict__ W,
                    const float* __restrict__ bias,
                    float* __restrict__ out) {
  __shared__ float Xs[16][68];
  __shared__ float Ws[16][68];
  const int r0 = blockIdx.y * 64;
  const int c0 = blockIdx.x * 64;
  const int tid = threadIdx.x;
  const int lrow = tid >> 2;
  const int lk4 = (tid & 3) * 4;
  const int tr = tid >> 4;
  const int tc = tid & 15;

  float acc[4][4] = {};
  for (int kt = 0; kt < 512; kt += 16) {
    float4 xv = *(const float4*)&Xa[(r0 + lrow) * 512 + kt + lk4];
    float4 wv = *(const float4*)&W[(c0 + lrow) * 512 + kt + lk4];
    __syncthreads();
    Xs[lk4 + 0][lrow] = xv.x; Xs[lk4 + 1][lrow] = xv.y;
    Xs[lk4 + 2][lrow] = xv.z; Xs[lk4 + 3][lrow] = xv.w;
    Ws[lk4 + 0][lrow] = wv.x; Ws[lk4 + 1][lrow] = wv.y;
    Ws[lk4 + 2][lrow] = wv.z; Ws[lk4 + 3][lrow] = wv.w;
    __syncthreads();
#pragma unroll
    for (int kk = 0; kk < 16; kk++) {
      float a[4], b[4];
      *(float4*)a = *(const float4*)&Xs[kk][tr * 4];
      *(float4*)b = *(const float4*)&Ws[kk][tc * 4];
#pragma unroll
      for (int ri = 0; ri < 4; ri++)
#pragma unroll
        for (int cj = 0; cj < 4; cj++)
          acc[ri][cj] = fmaf(a[ri], b[cj], acc[ri][cj]);
    }
  }
#pragma unroll
  for (int ri = 0; ri < 4; ri++) {
    const int r = r0 + tr * 4 + ri;
#pragma unroll
    for (int cj = 0; cj < 4; cj++) {
      const int j = c0 + tc * 4 + cj;
      out[(size_t)r * 512 + j] = acc[ri][cj] + bias[j];
    }
  }
}

extern "C" void kernel_launch(void* const* d_in, const int* in_sizes, int n_in,
                              void* d_out, int out_size, void* d_ws,
                              size_t ws_size, hipStream_t stream) {
  const float* query = (const float*)d_in[0];
  const float* key   = (const float*)d_in[1];
  const float* value = (const float*)d_in[2];
  const float* cbias = (const float*)d_in[3];
  const float* W     = (const float*)d_in[4];
  const float* pb    = (const float*)d_in[5];
  const float* out_w = (const float*)d_in[6];
  const float* out_b = (const float*)d_in[7];
  float* out = (float*)d_out;

  float* ws = (float*)d_ws;
  float* qh = ws;                                        // 524288 f
  float* kh = ws + 524288;                               // 524288 f
  unsigned short* vh = (unsigned short*)(ws + 1048576);  // 524288 bf16
  float* attn = ws + 1048576 + 262144;                   // 524288 f

  proj_kernel<<<dim3(24, 16), 256, 0, stream>>>(query, key, value, W, pb, qh,
                                                kh, vh);
  score_kernel<<<1024, 256, 0, stream>>>(qh, kh, vh, cbias, attn);
  outproj_kernel<<<dim3(8, 16), 256, 0, stream>>>(attn, out_w, out_b, out);
}

// Round 5
// 211.766 us; speedup vs baseline: 1.2264x; 1.1195x over previous
//
#include <hip/hip_runtime.h>
#include <math.h>

#define SCALING 0.125f

typedef __attribute__((ext_vector_type(8))) short short8;
typedef __attribute__((ext_vector_type(4))) float f32x4;

// round-to-nearest-even fp32 -> bf16 (single value)
static __device__ __forceinline__ unsigned short bf16r(float x) {
  unsigned int u = __float_as_uint(x);
  u += 0x7fffu + ((u >> 16) & 1u);
  return (unsigned short)(u >> 16);
}
// pack two fp32 -> bf16x2 (lo in low 16 bits) via v_perm_b32 merge
static __device__ __forceinline__ unsigned int pk_bf16(float lo, float hi) {
  unsigned int ua = __float_as_uint(lo);
  unsigned int ub = __float_as_uint(hi);
  ua += 0x7fffu + ((ua >> 16) & 1u);
  ub += 0x7fffu + ((ub >> 16) & 1u);
  return __builtin_amdgcn_perm(ub, ua, 0x07060302u);
}

// ---------------------------------------------------------------------------
// Kernel A: packed in-projection GEMM -> per-head layouts. K-loop is
// software-pipelined: next tile's global loads are in flight during compute.
//   j <  512 : q -> qh[i][t][hd] fp32  (scaled by 0.125)
//   j < 1024 : k -> kh[i][t][hd] fp32
//   j < 1536 : v -> vh[i][t][hd] bf16  (rounded once here)
// ---------------------------------------------------------------------------
__global__ __launch_bounds__(256)
void proj_kernel(const float* __restrict__ query,
                 const float* __restrict__ key,
                 const float* __restrict__ value,
                 const float* __restrict__ W,
                 const float* __restrict__ bias,
                 float* __restrict__ qh,
                 float* __restrict__ kh,
                 unsigned short* __restrict__ vh) {
  __shared__ float Xs[16][68];
  __shared__ float Ws[16][68];
  const int r0 = blockIdx.y * 64;
  const int c0 = blockIdx.x * 64;
  const int g = c0 >> 9;  // 0=q,1=k,2=v (uniform per block)
  const float* __restrict__ X = (g == 0) ? query : (g == 1) ? key : value;
  const int tid = threadIdx.x;
  const int lrow = tid >> 2;
  const int lk4 = (tid & 3) * 4;
  const int tr = tid >> 4;
  const int tc = tid & 15;

  float acc[4][4] = {};
  float4 xv = *(const float4*)&X[(r0 + lrow) * 512 + lk4];
  float4 wv = *(const float4*)&W[(c0 + lrow) * 512 + lk4];
  for (int kt = 0; kt < 512; kt += 16) {
    __syncthreads();
    Xs[lk4 + 0][lrow] = xv.x; Xs[lk4 + 1][lrow] = xv.y;
    Xs[lk4 + 2][lrow] = xv.z; Xs[lk4 + 3][lrow] = xv.w;
    Ws[lk4 + 0][lrow] = wv.x; Ws[lk4 + 1][lrow] = wv.y;
    Ws[lk4 + 2][lrow] = wv.z; Ws[lk4 + 3][lrow] = wv.w;
    __syncthreads();
    if (kt + 16 < 512) {  // prefetch next tile during compute
      xv = *(const float4*)&X[(r0 + lrow) * 512 + kt + 16 + lk4];
      wv = *(const float4*)&W[(c0 + lrow) * 512 + kt + 16 + lk4];
    }
#pragma unroll
    for (int kk = 0; kk < 16; kk++) {
      float a[4], b[4];
      *(float4*)a = *(const float4*)&Xs[kk][tr * 4];
      *(float4*)b = *(const float4*)&Ws[kk][tc * 4];
#pragma unroll
      for (int ri = 0; ri < 4; ri++)
#pragma unroll
        for (int cj = 0; cj < 4; cj++)
          acc[ri][cj] = fmaf(a[ri], b[cj], acc[ri][cj]);
    }
  }

#pragma unroll
  for (int ri = 0; ri < 4; ri++) {
    const int r = r0 + tr * 4 + ri;
    const int t = r >> 3;
    const int batch = r & 7;
#pragma unroll
    for (int cj = 0; cj < 4; cj++) {
      const int j = c0 + tc * 4 + cj;
      float val = acc[ri][cj] + bias[j];
      const int jj = j & 511;
      const int head = jj >> 6;
      const int hd = jj & 63;
      const int i = batch * 8 + head;
      const int idx = ((i << 7) + t) * 64 + hd;
      if (g == 0)      qh[idx] = val * SCALING;
      else if (g == 1) kh[idx] = val;
      else             vh[idx] = bf16r(val);
    }
  }
}

// ---------------------------------------------------------------------------
// Kernel B: one block per (batch, a, b-half). b split 2-ways: bias rows are
// disjoint per block (still read exactly once device-wide), acc shrinks to
// 32 regs and LDS to ~27 KB -> ~5 blocks/CU, giving the bias HBM stream
// 2.5x more outstanding requests. mean/max over c stays block-local.
// MFMA fragment indexing identical to the verified R2 kernel (b restricted).
// ---------------------------------------------------------------------------
__global__ __launch_bounds__(256)
void score_kernel(const float* __restrict__ qh,
                  const float* __restrict__ kh,
                  const unsigned short* __restrict__ vh,
                  const float* __restrict__ cbias,
                  float* __restrict__ fused) {
  __shared__ __align__(16) unsigned short Ks[64 * 72];
  __shared__ __align__(16) unsigned short Vs[128 * 72];

  const int bid = blockIdx.x;     // (batch*128 + a)*2 + bh
  const int bh = bid & 1;
  const int ab = bid >> 1;
  const int batch = ab >> 7;
  const int a = ab & 127;
  const int tid = threadIdx.x;
  const int w = tid >> 6;
  const int lane = tid & 63;
  const int quad = lane >> 4;
  const int n15 = lane & 15;
  const int col8 = (tid & 7) * 8;  // staging column (iteration-invariant)
  const int bglob = bh * 64 + w * 16 + n15;  // this lane's b for B-frag/epilogue

  const float* __restrict__ bp = cbias + (size_t)ab * 16384;

  for (int h = 0; h < 8; ++h) {
    const int i = batch * 8 + h;
    const float* __restrict__ kb = kh + (size_t)i * 8192 + (size_t)bh * 64 * 64;
    const uint4* __restrict__ vb4 = (const uint4*)(vh + (size_t)i * 8192);
    const float* __restrict__ qa = qh + ((size_t)i * 128 + a) * 64;

    // ---- stage: Vs full (copy), Ks b-half (k * q_a, packed bf16) ----
    f32x4 q0 = *(const f32x4*)&qa[col8];
    f32x4 q1 = *(const f32x4*)&qa[col8 + 4];
#pragma unroll
    for (int j = 0; j < 4; ++j) {
      const int gg = j * 256 + tid;  // 0..1023 groups of 8 (V rows 0..127)
      const int row = gg >> 3;
      *(uint4*)&Vs[row * 72 + col8] = vb4[gg];
    }
#pragma unroll
    for (int j = 0; j < 2; ++j) {
      const int gg = j * 256 + tid;  // 0..511 groups of 8 (K local rows 0..63)
      const int row = gg >> 3;
      f32x4 k0 = *(const f32x4*)&kb[8 * gg];
      f32x4 k1 = *(const f32x4*)&kb[8 * gg + 4];
      k0 *= q0;
      k1 *= q1;
      uint4 pk;
      pk.x = pk_bf16(k0[0], k0[1]);
      pk.y = pk_bf16(k0[2], k0[3]);
      pk.z = pk_bf16(k1[0], k1[1]);
      pk.w = pk_bf16(k1[2], k1[3]);
      *(uint4*)&Ks[row * 72 + col8] = pk;
    }
    __syncthreads();

    // ---- MFMA: S^T[c, b] = sum_hd v[c,hd] * (k[b,hd]*qa[hd]) ----
    short8 bf0 = *(const short8*)&Ks[(w * 16 + n15) * 72 + quad * 8];
    short8 bf1 = *(const short8*)&Ks[(w * 16 + n15) * 72 + 32 + quad * 8];

    f32x4 acc[8];
#pragma unroll
    for (int ic = 0; ic < 8; ++ic) acc[ic] = (f32x4){0.f, 0.f, 0.f, 0.f};
#pragma unroll
    for (int ic = 0; ic < 8; ++ic) {
      short8 a0 = *(const short8*)&Vs[(ic * 16 + n15) * 72 + quad * 8];
      short8 a1 = *(const short8*)&Vs[(ic * 16 + n15) * 72 + 32 + quad * 8];
      acc[ic] = __builtin_amdgcn_mfma_f32_16x16x32_bf16(a0, bf0, acc[ic], 0, 0, 0);
      acc[ic] = __builtin_amdgcn_mfma_f32_16x16x32_bf16(a1, bf1, acc[ic], 0, 0, 0);
    }
    __syncthreads();  // all LDS reads done before next head's staging

    // ---- bias add + mean/max over c (8 independent dwordx4 loads) ----
    float fsum = 0.f, fmx = -INFINITY;
#pragma unroll
    for (int ic = 0; ic < 8; ++ic) {
      f32x4 bb = *(const f32x4*)&bp[bglob * 128 + ic * 16 + quad * 4];
#pragma unroll
      for (int r = 0; r < 4; ++r) {
        const float v = acc[ic][r] + bb[r];
        fsum += v;
        fmx = fmaxf(fmx, v);
      }
    }
    fsum += __shfl_xor(fsum, 16, 64);
    fmx = fmaxf(fmx, __shfl_xor(fmx, 16, 64));
    fsum += __shfl_xor(fsum, 32, 64);
    fmx = fmaxf(fmx, __shfl_xor(fmx, 32, 64));
    if (quad == 0)
      fused[((size_t)i * 128 + a) * 128 + bglob] = fsum * (1.0f / 128.0f) + fmx;
  }
}

// ---------------------------------------------------------------------------
// Kernel C: softmax over b + attn[i,a,:] = sum_b w[b] * q[i,b,:]
// (verified round-2 kernel, unchanged)
// ---------------------------------------------------------------------------
__global__ __launch_bounds__(64)
void softmax_attn_kernel(const float* __restrict__ fused,
                         const float* __restrict__ qh,
                         float* __restrict__ attn) {
  const int bid = blockIdx.x;  // i*128 + a
  const int i = bid >> 7;
  const int a = bid & 127;
  const int lane = threadIdx.x;
  const float* __restrict__ fr = fused + (size_t)bid * 128;
  float f0 = fr[lane], f1 = fr[lane + 64];
  float m = fmaxf(f0, f1);
#pragma unroll
  for (int off = 32; off >= 1; off >>= 1) m = fmaxf(m, __shfl_xor(m, off, 64));
  const float e0 = expf(f0 - m), e1 = expf(f1 - m);
  float s = e0 + e1;
#pragma unroll
  for (int off = 32; off >= 1; off >>= 1) s += __shfl_xor(s, off, 64);
  const float inv = 1.0f / s;
  __shared__ float w[128];
  w[lane] = e0 * inv;
  w[lane + 64] = e1 * inv;
  __syncthreads();
  const float* __restrict__ qp = qh + (size_t)i * 128 * 64 + lane;
  float acc = 0.0f;
#pragma unroll 4
  for (int b = 0; b < 128; b++) acc = fmaf(w[b], qp[b * 64], acc);
  const int batch = i >> 3, head = i & 7;
  attn[((size_t)a * 8 + batch) * 512 + head * 64 + lane] = acc;
}

// ---------------------------------------------------------------------------
// Kernel D: output projection, software-pipelined like Kernel A.
// ---------------------------------------------------------------------------
__global__ __launch_bounds__(256)
void outproj_kernel(const float* __restrict__ Xa,
                    const float* __restrict__ W,
                    const float* __restrict__ bias,
                    float* __restrict__ out) {
  __shared__ float Xs[16][68];
  __shared__ float Ws[16][68];
  const int r0 = blockIdx.y * 64;
  const int c0 = blockIdx.x * 64;
  const int tid = threadIdx.x;
  const int lrow = tid >> 2;
  const int lk4 = (tid & 3) * 4;
  const int tr = tid >> 4;
  const int tc = tid & 15;

  float acc[4][4] = {};
  float4 xv = *(const float4*)&Xa[(r0 + lrow) * 512 + lk4];
  float4 wv = *(const float4*)&W[(c0 + lrow) * 512 + lk4];
  for (int kt = 0; kt < 512; kt += 16) {
    __syncthreads();
    Xs[lk4 + 0][lrow] = xv.x; Xs[lk4 + 1][lrow] = xv.y;
    Xs[lk4 + 2][lrow] = xv.z; Xs[lk4 + 3][lrow] = xv.w;
    Ws[lk4 + 0][lrow] = wv.x; Ws[lk4 + 1][lrow] = wv.y;
    Ws[lk4 + 2][lrow] = wv.z; Ws[lk4 + 3][lrow] = wv.w;
    __syncthreads();
    if (kt + 16 < 512) {
      xv = *(const float4*)&Xa[(r0 + lrow) * 512 + kt + 16 + lk4];
      wv = *(const float4*)&W[(c0 + lrow) * 512 + kt + 16 + lk4];
    }
#pragma unroll
    for (int kk = 0; kk < 16; kk++) {
      float a[4], b[4];
      *(float4*)a = *(const float4*)&Xs[kk][tr * 4];
      *(float4*)b = *(const float4*)&Ws[kk][tc * 4];
#pragma unroll
      for (int ri = 0; ri < 4; ri++)
#pragma unroll
        for (int cj = 0; cj < 4; cj++)
          acc[ri][cj] = fmaf(a[ri], b[cj], acc[ri][cj]);
    }
  }
#pragma unroll
  for (int ri = 0; ri < 4; ri++) {
    const int r = r0 + tr * 4 + ri;
#pragma unroll
    for (int cj = 0; cj < 4; cj++) {
      const int j = c0 + tc * 4 + cj;
      out[(size_t)r * 512 + j] = acc[ri][cj] + bias[j];
    }
  }
}

extern "C" void kernel_launch(void* const* d_in, const int* in_sizes, int n_in,
                              void* d_out, int out_size, void* d_ws,
                              size_t ws_size, hipStream_t stream) {
  const float* query = (const float*)d_in[0];
  const float* key   = (const float*)d_in[1];
  const float* value = (const float*)d_in[2];
  const float* cbias = (const float*)d_in[3];
  const float* W     = (const float*)d_in[4];
  const float* pb    = (const float*)d_in[5];
  const float* out_w = (const float*)d_in[6];
  const float* out_b = (const float*)d_in[7];
  float* out = (float*)d_out;

  float* ws = (float*)d_ws;
  float* qh = ws;                                        // 524288 f
  float* kh = ws + 524288;                               // 524288 f
  unsigned short* vh = (unsigned short*)(ws + 1048576);  // 524288 bf16
  float* fusedb = ws + 1048576 + 262144;                 // 1048576 f
  float* attn = fusedb + 1048576;                        // 524288 f

  proj_kernel<<<dim3(24, 16), 256, 0, stream>>>(query, key, value, W, pb, qh,
                                                kh, vh);
  score_kernel<<<2048, 256, 0, stream>>>(qh, kh, vh, cbias, fusedb);
  softmax_attn_kernel<<<8192, 64, 0, stream>>>(fusedb, qh, attn);
  outproj_kernel<<<dim3(8, 16), 256, 0, stream>>>(attn, out_w, out_b, out);
}